// Round 18
// baseline (154.992 us; speedup 1.0000x reference)
//
#include <hip/hip_runtime.h>
#include <stdint.h>

#define B_SZ 8192
#define N_SZ 256
#define H_SZ 2048
#define LOG2PI_F 1.8378770664093453f
#define BETA_F 0.99f

typedef unsigned short ushort_t;
typedef __attribute__((ext_vector_type(8))) __bf16 bf16x8;
typedef __attribute__((ext_vector_type(4))) float f32x4;
typedef __attribute__((ext_vector_type(8))) ushort_t u16x8;

__device__ __forceinline__ ushort_t f2bf(float f) {
    unsigned int u = __float_as_uint(f);
    unsigned int r = (u + 0x7FFFu + ((u >> 16) & 1u)) >> 16;  // RNE
    return (ushort_t)r;
}

__device__ __forceinline__ float fast_tanh(float v) {
    float ex = __expf(2.0f * v);
    return 1.0f - __fdividef(2.0f, ex + 1.0f);
}

__device__ __forceinline__ void async_ld16(const void* g, const char* lds_uniform) {
    __builtin_amdgcn_global_load_lds(
        (const __attribute__((address_space(1))) void*)g,
        (__attribute__((address_space(3))) void*)lds_uniform,
        16, 0, 0);
}

// GEMM1: tanh(x@W1+b1) -> hp (k-permuted [H/8][B][8]). 128x128 tiles, BK=64.
// 1D grid 1024 (exactly 4/CU), XCD swizzle. LDS-transposed 16B stores.
__global__ __launch_bounds__(256, 4)
void gemm1_kernel(const ushort_t* __restrict__ xb, const ushort_t* __restrict__ W1p,
                  const float* __restrict__ b1, ushort_t* __restrict__ hp)
{
    __shared__ __align__(16) char smem[34816];  // loop: sA 16K + sB 16K; epi: st 34K
    char* sA = smem;           // [8 kq][128 m][8] bf16 = 16 KB
    char* sB = smem + 16384;   // [8 kq][128 n][8] bf16 = 16 KB
    const int tid = threadIdx.x;
    const int lane = tid & 63;
    const int w = tid >> 6;
    const int q = lane >> 4;
    const int rlo = lane & 15;
    const int wr = w >> 1, wc = w & 1;

    const int bid = blockIdx.x;
    const int r8 = bid & 7;
    const int u = bid >> 3;       // 0..127
    const int cb = u & 15;        // col block 0..15
    const int tb = u >> 4;        // 0..7
    const int row0 = (r8 + 8 * tb) * 128;
    const int n0 = cb * 128;

    f32x4 acc[4][4];
#pragma unroll
    for (int i = 0; i < 4; ++i)
#pragma unroll
        for (int j = 0; j < 4; ++j)
            acc[i][j] = f32x4{0.f, 0.f, 0.f, 0.f};

    for (int k0 = 0; k0 < N_SZ; k0 += 64) {
        __syncthreads();
#pragma unroll
        for (int r = 0; r < 4; ++r) {
            int c = r * 256 + tid;
            int kq = c >> 7, m = c & 127;
            async_ld16(xb + (size_t)(row0 + m) * N_SZ + k0 + kq * 8, sA + (c << 4));
        }
        int ko0 = k0 >> 3;
#pragma unroll
        for (int r = 0; r < 4; ++r) {
            int c = r * 256 + tid;
            int kq = c >> 7, n = c & 127;
            async_ld16(W1p + ((size_t)(ko0 + kq) * H_SZ + n0 + n) * 8, sB + (c << 4));
        }
        __syncthreads();

#pragma unroll
        for (int ks = 0; ks < 2; ++ks) {
            int kq = ks * 4 + q;
            bf16x8 af[4], bfr[4];
#pragma unroll
            for (int i = 0; i < 4; ++i)
                af[i] = *(const bf16x8*)(sA + (((kq << 7) + wr * 64 + i * 16 + rlo) << 4));
#pragma unroll
            for (int j = 0; j < 4; ++j)
                bfr[j] = *(const bf16x8*)(sB + (((kq << 7) + wc * 64 + j * 16 + rlo) << 4));
#pragma unroll
            for (int i = 0; i < 4; ++i)
#pragma unroll
                for (int j = 0; j < 4; ++j)
                    acc[i][j] = __builtin_amdgcn_mfma_f32_16x16x32_bf16(af[i], bfr[j], acc[i][j], 0, 0, 0);
        }
    }

    __syncthreads();  // done with sA/sB reads; reuse LDS as transpose buffer
    ushort_t* st = (ushort_t*)smem;  // [128 rows][stride 136] bf16
#pragma unroll
    for (int j = 0; j < 4; ++j) {
        int coll = wc * 64 + j * 16 + rlo;
        float bv = b1[n0 + coll];
#pragma unroll
        for (int i = 0; i < 4; ++i) {
            int rowl = wr * 64 + i * 16 + q * 4;
#pragma unroll
            for (int rr = 0; rr < 4; ++rr)
                st[(rowl + rr) * 136 + coll] = f2bf(fast_tanh(acc[i][j][rr] + bv));
        }
    }
    __syncthreads();
    // coalesced store: 2048 chunks x 16B -> hp[(n0/8+ko)*B + row0+m]*8
#pragma unroll
    for (int r = 0; r < 8; ++r) {
        int c = r * 256 + tid;
        int m = c & 127, ko = c >> 7;
        u16x8 v = *(const u16x8*)(st + m * 136 + ko * 8);
        *(u16x8*)(hp + ((size_t)((n0 >> 3) + ko) * B_SZ + row0 + m) * 8) = v;
    }
}

// GEMM2 split-K 2-way: f01[zb] = h[:, zb*1024..+1024) @ W2[zb half] (no bias).
// 64x128 tiles, BK=64, K=1024/block, 24 KB LDS. grid 1024 (4/CU), XCD swizzle.
// Combine (f0+f1+b2) happens in vmu_epilogue.
__global__ __launch_bounds__(256, 4)
void gemm2_kernel(const ushort_t* __restrict__ hp, const ushort_t* __restrict__ W2p,
                  float* __restrict__ f01)
{
    __shared__ __align__(16) char smem[24576];
    char* sA = smem;          // [8 kq][64 m][8] bf16 = 8 KB
    char* sB = smem + 8192;   // [8 kq][128 n][8] bf16 = 16 KB
    const int tid = threadIdx.x;
    const int lane = tid & 63;
    const int w = tid >> 6;
    const int q = lane >> 4;
    const int rlo = lane & 15;
    const int wr = w >> 1, wc = w & 1;

    const int bid = blockIdx.x;
    const int r8 = bid & 7;
    const int u = bid >> 3;      // 0..127
    const int zb = u & 1;        // K half
    const int v = u >> 1;        // 0..63
    const int cb = v & 3;
    const int tb = v >> 2;       // 0..15
    const int row0 = (r8 + 8 * tb) * 64;
    const int n0 = cb * 128;
    const int kbase = zb * (H_SZ / 2);
    float* f = f01 + (size_t)zb * B_SZ * 512;

    f32x4 acc[2][4];
#pragma unroll
    for (int i = 0; i < 2; ++i)
#pragma unroll
        for (int j = 0; j < 4; ++j)
            acc[i][j] = f32x4{0.f, 0.f, 0.f, 0.f};

    for (int k0 = kbase; k0 < kbase + H_SZ / 2; k0 += 64) {
        __syncthreads();
        int ko0 = k0 >> 3;
#pragma unroll
        for (int r = 0; r < 2; ++r) {   // A: 512 chunks from hp, [kq][m][8]
            int c = r * 256 + tid;
            int kq = c >> 6, m = c & 63;
            async_ld16(hp + ((size_t)(ko0 + kq) * B_SZ + row0 + m) * 8, sA + (c << 4));
        }
#pragma unroll
        for (int r = 0; r < 4; ++r) {   // B: 1024 chunks, [kq][n][8]
            int c = r * 256 + tid;
            int kq = c >> 7, n = c & 127;
            async_ld16(W2p + ((size_t)(ko0 + kq) * 512 + n0 + n) * 8, sB + (c << 4));
        }
        __syncthreads();

#pragma unroll
        for (int ks = 0; ks < 2; ++ks) {
            int kq = ks * 4 + q;
            bf16x8 af[2], bfr[4];
#pragma unroll
            for (int i = 0; i < 2; ++i)
                af[i] = *(const bf16x8*)(sA + (((kq << 6) + wr * 32 + i * 16 + rlo) << 4));
#pragma unroll
            for (int j = 0; j < 4; ++j)
                bfr[j] = *(const bf16x8*)(sB + (((kq << 7) + wc * 64 + j * 16 + rlo) << 4));
#pragma unroll
            for (int i = 0; i < 2; ++i)
#pragma unroll
                for (int j = 0; j < 4; ++j)
                    acc[i][j] = __builtin_amdgcn_mfma_f32_16x16x32_bf16(af[i], bfr[j], acc[i][j], 0, 0, 0);
        }
    }

    // clean f32 stores (64B segments per quad)
#pragma unroll
    for (int j = 0; j < 4; ++j) {
        int col = n0 + wc * 64 + j * 16 + rlo;
#pragma unroll
        for (int i = 0; i < 2; ++i) {
            int rowb = row0 + wr * 32 + i * 16 + q * 4;
#pragma unroll
            for (int rr = 0; rr < 4; ++rr)
                f[(size_t)(rowb + rr) * 512 + col] = acc[i][j][rr];
        }
    }
}

// Fused Vx + Vmu + epilogue, 512 blocks x 16 rows. Stage 1 computes BOTH
// xb@Wv and mu@Wv rowsumsq sharing the Wv B-fragments; mu = f0+f1+b2
// built in-register (split-K combine fused here).
__global__ __launch_bounds__(256)
void vmu_epilogue_kernel(const ushort_t* __restrict__ xb, const float* __restrict__ f01,
                         const ushort_t* __restrict__ Wvp, const float* __restrict__ b2,
                         const float* __restrict__ y, const float* __restrict__ eps,
                         float* __restrict__ out, float* __restrict__ partials)
{
    __shared__ float vsx[4][16];
    __shared__ float vsm[4][16];
    __shared__ float vxs[16];
    __shared__ float vms[16];
    __shared__ float red[4];
    const int tid = threadIdx.x;
    const int lane = tid & 63;
    const int w = tid >> 6;
    const int q = lane >> 4;
    const int rlo = lane & 15;
    const int r0 = blockIdx.x * 16;
    const size_t FB = (size_t)B_SZ * 512;

    // ---- stage 1: Vx & Vmu via MFMA (16x64 tile per wave, shared B) ----
    f32x4 accx[4], accm[4];
#pragma unroll
    for (int j = 0; j < 4; ++j) {
        accx[j] = f32x4{0.f, 0.f, 0.f, 0.f};
        accm[j] = f32x4{0.f, 0.f, 0.f, 0.f};
    }

    const ushort_t* ax = xb + (size_t)(r0 + rlo) * N_SZ + q * 8;
    const float* f0a = f01 + (size_t)(r0 + rlo) * 512 + q * 8;
    const float* f1a = f0a + FB;
    const float* b2q = b2 + q * 8;
    const ushort_t* b0 = Wvp + ((size_t)q * N_SZ + w * 64 + rlo) * 8;
#pragma unroll
    for (int s = 0; s < 8; ++s) {
        bf16x8 afx = *(const bf16x8*)(ax + s * 32);
        f32x4 p0 = *(const f32x4*)(f0a + s * 32);
        f32x4 p1 = *(const f32x4*)(f0a + s * 32 + 4);
        f32x4 q0 = *(const f32x4*)(f1a + s * 32);
        f32x4 q1 = *(const f32x4*)(f1a + s * 32 + 4);
        f32x4 b0v = *(const f32x4*)(b2q + s * 32);
        f32x4 b1v = *(const f32x4*)(b2q + s * 32 + 4);
        u16x8 am;
#pragma unroll
        for (int e = 0; e < 4; ++e) {
            am[e]     = f2bf(p0[e] + q0[e] + b0v[e]);
            am[4 + e] = f2bf(p1[e] + q1[e] + b1v[e]);
        }
        bf16x8 afm = *(const bf16x8*)&am;
        bf16x8 bfr[4];
#pragma unroll
        for (int j = 0; j < 4; ++j)
            bfr[j] = *(const bf16x8*)(b0 + s * 4 * N_SZ * 8 + j * 128);
#pragma unroll
        for (int j = 0; j < 4; ++j) {
            accx[j] = __builtin_amdgcn_mfma_f32_16x16x32_bf16(afx, bfr[j], accx[j], 0, 0, 0);
            accm[j] = __builtin_amdgcn_mfma_f32_16x16x32_bf16(afm, bfr[j], accm[j], 0, 0, 0);
        }
    }
#pragma unroll
    for (int rr = 0; rr < 4; ++rr) {
        float sx = 0.f, sm = 0.f;
#pragma unroll
        for (int j = 0; j < 4; ++j) {
            float vx_ = accx[j][rr]; sx += vx_ * vx_;
            float vm_ = accm[j][rr]; sm += vm_ * vm_;
        }
#pragma unroll
        for (int m = 1; m < 16; m <<= 1) {
            sx += __shfl_xor(sx, m, 64);
            sm += __shfl_xor(sm, m, 64);
        }
        if (rlo == 0) {
            vsx[w][q * 4 + rr] = sx;
            vsm[w][q * 4 + rr] = sm;
        }
    }
    __syncthreads();
    if (tid < 16) {
        vxs[tid] = 1e-3f + vsx[0][tid] + vsx[1][tid] + vsx[2][tid] + vsx[3][tid];
        vms[tid] = 1e-3f + vsm[0][tid] + vsm[1][tid] + vsm[2][tid] + vsm[3][tid];
    }
    __syncthreads();

    // ---- stage 2: epilogue over 16 rows (mu/lv = f0+f1+b2) ----
    float t = 0.f;
    const int n = tid;
    const float b2mu = b2[n];
    const float b2lv = b2[256 + n];
#pragma unroll 4
    for (int r = 0; r < 16; ++r) {
        size_t row = (size_t)(r0 + r);
        float mu = f01[row * 512 + n] + f01[FB + row * 512 + n] + b2mu;
        float lv = f01[row * 512 + 256 + n] + f01[FB + row * 512 + 256 + n] + b2lv;
        float var = expf(lv);
        float Vx = vxs[r];
        float Vmu = vms[r];
        float scale = fminf(BETA_F * Vx, Vmu) / Vmu;
        float mus = mu * scale;
        out[row * 256 + n] = mus + sqrtf(var) * eps[row * 256 + n];
        float d = y[row * 256 + n] - mus;
        t += lv + d * d / var;
    }
#pragma unroll
    for (int m = 32; m >= 1; m >>= 1) t += __shfl_down(t, m, 64);
    if (lane == 0) red[w] = t;
    __syncthreads();
    if (tid == 0)
        partials[blockIdx.x] = red[0] + red[1] + red[2] + red[3];
}

// sum 512 partials -> logp_y scalar.
__global__ __launch_bounds__(256)
void reduce_kernel(const float* __restrict__ partials, float* __restrict__ out)
{
    int tid = threadIdx.x;
    float s = partials[tid] + partials[tid + 256];
#pragma unroll
    for (int m = 32; m >= 1; m >>= 1) s += __shfl_down(s, m, 64);
    __shared__ float red[4];
    if ((tid & 63) == 0) red[tid >> 6] = s;
    __syncthreads();
    if (tid == 0)
        out[(size_t)B_SZ * N_SZ] =
            0.5f * (red[0] + red[1] + red[2] + red[3] +
                    (float)N_SZ * LOG2PI_F * (float)B_SZ);
}

// Conversion, fully coalesced: one thread per 8-element k-chunk.
__global__ __launch_bounds__(256)
void convert_kernel(const float* __restrict__ x, const float* __restrict__ W1,
                    const float* __restrict__ W2, const float* __restrict__ Wv,
                    ushort_t* __restrict__ xb, ushort_t* __restrict__ W1p,
                    ushort_t* __restrict__ W2p, ushort_t* __restrict__ Wvp)
{
    const int XC = 262144, W1C = 65536, W2C = 131072;
    int c = blockIdx.x * 256 + threadIdx.x;
    if (c < XC) {
        f32x4 a = *(const f32x4*)(x + (size_t)c * 8);
        f32x4 b = *(const f32x4*)(x + (size_t)c * 8 + 4);
        u16x8 o;
#pragma unroll
        for (int i = 0; i < 4; ++i) { o[i] = f2bf(a[i]); o[4 + i] = f2bf(b[i]); }
        *(u16x8*)(xb + (size_t)c * 8) = o;
    } else if (c < XC + W1C) {
        int d = c - XC;
        int ko = d >> 11, n = d & 2047;
        u16x8 o;
#pragma unroll
        for (int ki = 0; ki < 8; ++ki)
            o[ki] = f2bf(W1[(size_t)(ko * 8 + ki) * H_SZ + n]);
        *(u16x8*)(W1p + (size_t)d * 8) = o;
    } else if (c < XC + W1C + W2C) {
        int d = c - XC - W1C;
        int ko = d >> 9, n = d & 511;
        u16x8 o;
#pragma unroll
        for (int ki = 0; ki < 8; ++ki)
            o[ki] = f2bf(W2[(size_t)(ko * 8 + ki) * 512 + n]);
        *(u16x8*)(W2p + (size_t)d * 8) = o;
    } else {
        int d = c - XC - W1C - W2C;
        int ko = d >> 8, n = d & 255;
        u16x8 o;
#pragma unroll
        for (int ki = 0; ki < 8; ++ki)
            o[ki] = f2bf(Wv[(size_t)(ko * 8 + ki) * N_SZ + n]);
        *(u16x8*)(Wvp + (size_t)d * 8) = o;
    }
}

extern "C" void kernel_launch(void* const* d_in, const int* in_sizes, int n_in,
                              void* d_out, int out_size, void* d_ws, size_t ws_size,
                              hipStream_t stream)
{
    const float* x   = (const float*)d_in[0];
    const float* y   = (const float*)d_in[1];
    const float* eps = (const float*)d_in[2];
    const float* W1  = (const float*)d_in[3];
    const float* b1  = (const float*)d_in[4];
    const float* W2  = (const float*)d_in[5];
    const float* b2  = (const float*)d_in[6];
    const float* Wv  = (const float*)d_in[7];
    float* out = (float*)d_out;

    char* ws = (char*)d_ws;
    size_t off = 0;
    auto alloc = [&](size_t bytes) {
        char* p = ws + off;
        off += (bytes + 255) & ~(size_t)255;
        return p;
    };
    ushort_t* xb  = (ushort_t*)alloc((size_t)B_SZ * N_SZ * 2);
    ushort_t* W1p = (ushort_t*)alloc((size_t)N_SZ * H_SZ * 2);
    ushort_t* W2p = (ushort_t*)alloc((size_t)H_SZ * 512 * 2);
    ushort_t* Wvp = (ushort_t*)alloc((size_t)N_SZ * N_SZ * 2);
    ushort_t* hp  = (ushort_t*)alloc((size_t)B_SZ * H_SZ * 2);
    float*    f01 = (float*)alloc((size_t)2 * B_SZ * 512 * 4);
    float*    partials = (float*)alloc(512 * 4);

    const int TOTALC = 262144 + 65536 + 131072 + 8192;  // 466944 chunks
    convert_kernel<<<TOTALC / 256, 256, 0, stream>>>(x, W1, W2, Wv, xb, W1p, W2p, Wvp);

    // h_p = tanh(x@W1 + b1) k-permuted, 1024 blocks (4/CU), BK=64
    gemm1_kernel<<<1024, 256, 0, stream>>>(xb, W1p, b1, hp);
    // f01[z] = h@W2 K-halves (split-K 2-way, no bias), 1024 blocks (4/CU)
    gemm2_kernel<<<1024, 256, 0, stream>>>(hp, W2p, f01);
    // Vx + Vmu + epilogue fused (split-K combine + shared Wv B-frags)
    vmu_epilogue_kernel<<<512, 256, 0, stream>>>(xb, f01, Wvp, b2, y, eps, out, partials);
    reduce_kernel<<<1, 256, 0, stream>>>(partials, out);
}

// Round 19
// 151.473 us; speedup vs baseline: 1.0232x; 1.0232x over previous
//
#include <hip/hip_runtime.h>
#include <stdint.h>

#define B_SZ 8192
#define N_SZ 256
#define H_SZ 2048
#define LOG2PI_F 1.8378770664093453f
#define BETA_F 0.99f

typedef unsigned short ushort_t;
typedef __attribute__((ext_vector_type(8))) __bf16 bf16x8;
typedef __attribute__((ext_vector_type(4))) float f32x4;
typedef __attribute__((ext_vector_type(8))) ushort_t u16x8;

__device__ __forceinline__ ushort_t f2bf(float f) {
    unsigned int u = __float_as_uint(f);
    unsigned int r = (u + 0x7FFFu + ((u >> 16) & 1u)) >> 16;  // RNE
    return (ushort_t)r;
}

__device__ __forceinline__ float fast_tanh(float v) {
    float ex = __expf(2.0f * v);
    return 1.0f - __fdividef(2.0f, ex + 1.0f);
}

__device__ __forceinline__ void async_ld16(const void* g, const char* lds_uniform) {
    __builtin_amdgcn_global_load_lds(
        (const __attribute__((address_space(1))) void*)g,
        (__attribute__((address_space(3))) void*)lds_uniform,
        16, 0, 0);
}

// GEMM1: tanh(x@W1+b1) -> hp (k-permuted [H/8][B][8]). 128x128 tiles, BK=64.
// 1D grid 1024 (exactly 4/CU), XCD swizzle. LDS-transposed 16B stores.
__global__ __launch_bounds__(256, 4)
void gemm1_kernel(const ushort_t* __restrict__ xb, const ushort_t* __restrict__ W1p,
                  const float* __restrict__ b1, ushort_t* __restrict__ hp)
{
    __shared__ __align__(16) char smem[34816];  // loop: sA 16K + sB 16K; epi: st 34K
    char* sA = smem;           // [8 kq][128 m][8] bf16 = 16 KB
    char* sB = smem + 16384;   // [8 kq][128 n][8] bf16 = 16 KB
    const int tid = threadIdx.x;
    const int lane = tid & 63;
    const int w = tid >> 6;
    const int q = lane >> 4;
    const int rlo = lane & 15;
    const int wr = w >> 1, wc = w & 1;

    const int bid = blockIdx.x;
    const int r8 = bid & 7;
    const int u = bid >> 3;       // 0..127
    const int cb = u & 15;        // col block 0..15
    const int tb = u >> 4;        // 0..7
    const int row0 = (r8 + 8 * tb) * 128;
    const int n0 = cb * 128;

    f32x4 acc[4][4];
#pragma unroll
    for (int i = 0; i < 4; ++i)
#pragma unroll
        for (int j = 0; j < 4; ++j)
            acc[i][j] = f32x4{0.f, 0.f, 0.f, 0.f};

    for (int k0 = 0; k0 < N_SZ; k0 += 64) {
        __syncthreads();
#pragma unroll
        for (int r = 0; r < 4; ++r) {
            int c = r * 256 + tid;
            int kq = c >> 7, m = c & 127;
            async_ld16(xb + (size_t)(row0 + m) * N_SZ + k0 + kq * 8, sA + (c << 4));
        }
        int ko0 = k0 >> 3;
#pragma unroll
        for (int r = 0; r < 4; ++r) {
            int c = r * 256 + tid;
            int kq = c >> 7, n = c & 127;
            async_ld16(W1p + ((size_t)(ko0 + kq) * H_SZ + n0 + n) * 8, sB + (c << 4));
        }
        __syncthreads();

#pragma unroll
        for (int ks = 0; ks < 2; ++ks) {
            int kq = ks * 4 + q;
            bf16x8 af[4], bfr[4];
#pragma unroll
            for (int i = 0; i < 4; ++i)
                af[i] = *(const bf16x8*)(sA + (((kq << 7) + wr * 64 + i * 16 + rlo) << 4));
#pragma unroll
            for (int j = 0; j < 4; ++j)
                bfr[j] = *(const bf16x8*)(sB + (((kq << 7) + wc * 64 + j * 16 + rlo) << 4));
#pragma unroll
            for (int i = 0; i < 4; ++i)
#pragma unroll
                for (int j = 0; j < 4; ++j)
                    acc[i][j] = __builtin_amdgcn_mfma_f32_16x16x32_bf16(af[i], bfr[j], acc[i][j], 0, 0, 0);
        }
    }

    __syncthreads();  // done with sA/sB reads; reuse LDS as transpose buffer
    ushort_t* st = (ushort_t*)smem;  // [128 rows][stride 136] bf16
#pragma unroll
    for (int j = 0; j < 4; ++j) {
        int coll = wc * 64 + j * 16 + rlo;
        float bv = b1[n0 + coll];
#pragma unroll
        for (int i = 0; i < 4; ++i) {
            int rowl = wr * 64 + i * 16 + q * 4;
#pragma unroll
            for (int rr = 0; rr < 4; ++rr)
                st[(rowl + rr) * 136 + coll] = f2bf(fast_tanh(acc[i][j][rr] + bv));
        }
    }
    __syncthreads();
    // coalesced store: 2048 chunks x 16B -> hp[(n0/8+ko)*B + row0+m]*8
#pragma unroll
    for (int r = 0; r < 8; ++r) {
        int c = r * 256 + tid;
        int m = c & 127, ko = c >> 7;
        u16x8 v = *(const u16x8*)(st + m * 136 + ko * 8);
        *(u16x8*)(hp + ((size_t)((n0 >> 3) + ko) * B_SZ + row0 + m) * 8) = v;
    }
}

// GEMM2: f = h@W2 + b2, mub = bf16(f[:, :256]) via LDS-transposed 16B stores.
// A from hp (k-permuted). 64x128 tiles, BK=128 (16 iters). grid 512, XCD swizzle.
__global__ __launch_bounds__(256, 2)
void gemm2_kernel(const ushort_t* __restrict__ hp, const ushort_t* __restrict__ W2p,
                  const float* __restrict__ b2, float* __restrict__ f,
                  ushort_t* __restrict__ mub)
{
    __shared__ __align__(16) char smem[49152];
    char* sA = smem;           // [16 kq][64 m][8] bf16 = 16 KB
    char* sB = smem + 16384;   // [16 kq][128 n][8] bf16 = 32 KB
    const int tid = threadIdx.x;
    const int lane = tid & 63;
    const int w = tid >> 6;
    const int q = lane >> 4;
    const int rlo = lane & 15;
    const int wr = w >> 1, wc = w & 1;

    const int bid = blockIdx.x;
    const int r8 = bid & 7;
    const int u = bid >> 3;
    const int cb = u & 3;
    const int tb = u >> 2;
    const int row0 = (r8 + 8 * tb) * 64;
    const int n0 = cb * 128;

    f32x4 acc[2][4];
#pragma unroll
    for (int i = 0; i < 2; ++i)
#pragma unroll
        for (int j = 0; j < 4; ++j)
            acc[i][j] = f32x4{0.f, 0.f, 0.f, 0.f};

    for (int k0 = 0; k0 < H_SZ; k0 += 128) {
        __syncthreads();
        int ko0 = k0 >> 3;
#pragma unroll
        for (int r = 0; r < 4; ++r) {   // A: 1024 chunks from hp, [kq][m][8]
            int c = r * 256 + tid;
            int kq = c >> 6, m = c & 63;
            async_ld16(hp + ((size_t)(ko0 + kq) * B_SZ + row0 + m) * 8, sA + (c << 4));
        }
#pragma unroll
        for (int r = 0; r < 8; ++r) {   // B: 2048 chunks, [kq][n][8]
            int c = r * 256 + tid;
            int kq = c >> 7, n = c & 127;
            async_ld16(W2p + ((size_t)(ko0 + kq) * 512 + n0 + n) * 8, sB + (c << 4));
        }
        __syncthreads();

#pragma unroll
        for (int ks = 0; ks < 4; ++ks) {
            int kq = ks * 4 + q;
            bf16x8 af[2], bfr[4];
#pragma unroll
            for (int i = 0; i < 2; ++i)
                af[i] = *(const bf16x8*)(sA + (((kq << 6) + wr * 32 + i * 16 + rlo) << 4));
#pragma unroll
            for (int j = 0; j < 4; ++j)
                bfr[j] = *(const bf16x8*)(sB + (((kq << 7) + wc * 64 + j * 16 + rlo) << 4));
#pragma unroll
            for (int i = 0; i < 2; ++i)
#pragma unroll
                for (int j = 0; j < 4; ++j)
                    acc[i][j] = __builtin_amdgcn_mfma_f32_16x16x32_bf16(af[i], bfr[j], acc[i][j], 0, 0, 0);
        }
    }

    // f32 stores (clean 64B segments per quad)
#pragma unroll
    for (int j = 0; j < 4; ++j) {
        int col = n0 + wc * 64 + j * 16 + rlo;
        float bv = b2[col];
#pragma unroll
        for (int i = 0; i < 2; ++i) {
            int rowb = row0 + wr * 32 + i * 16 + q * 4;
#pragma unroll
            for (int rr = 0; rr < 4; ++rr)
                f[(size_t)(rowb + rr) * 512 + col] = acc[i][j][rr] + bv;
        }
    }
    // mub (cols < 256 only, i.e. cb 0/1): LDS transpose -> coalesced 16B stores
    if (n0 < N_SZ) {
        __syncthreads();  // all waves done reading sA/sB
        ushort_t* st = (ushort_t*)smem;  // [64 rows][stride 136] bf16
#pragma unroll
        for (int j = 0; j < 4; ++j) {
            int coll = wc * 64 + j * 16 + rlo;
            float bv = b2[n0 + coll];
#pragma unroll
            for (int i = 0; i < 2; ++i) {
                int rowl = wr * 32 + i * 16 + q * 4;
#pragma unroll
                for (int rr = 0; rr < 4; ++rr)
                    st[(rowl + rr) * 136 + coll] = f2bf(acc[i][j][rr] + bv);
            }
        }
        __syncthreads();
        // 1024 chunks x 16B: chunk c -> row c>>4, col8 c&15 (256B contig/row)
#pragma unroll
        for (int r = 0; r < 4; ++r) {
            int c = r * 256 + tid;
            int m = c >> 4, c8 = c & 15;
            u16x8 v = *(const u16x8*)(st + m * 136 + c8 * 8);
            *(u16x8*)(mub + (size_t)(row0 + m) * N_SZ + n0 + c8 * 8) = v;
        }
    }
}

// Fused Vx + Vmu + epilogue, 512 blocks x 16 rows. Stage 1 computes BOTH
// xb@Wv and mub@Wv rowsumsq sharing the Wv B-fragments (B-loads halved).
__global__ __launch_bounds__(256)
void vmu_epilogue_kernel(const ushort_t* __restrict__ xb, const ushort_t* __restrict__ mub,
                         const ushort_t* __restrict__ Wvp,
                         const float* __restrict__ f, const float* __restrict__ y,
                         const float* __restrict__ eps,
                         float* __restrict__ out, float* __restrict__ partials)
{
    __shared__ float vsx[4][16];
    __shared__ float vsm[4][16];
    __shared__ float vxs[16];
    __shared__ float vms[16];
    __shared__ float red[4];
    const int tid = threadIdx.x;
    const int lane = tid & 63;
    const int w = tid >> 6;
    const int q = lane >> 4;
    const int rlo = lane & 15;
    const int r0 = blockIdx.x * 16;

    // ---- stage 1: Vx & Vmu via MFMA (16x64 tile per wave, shared B) ----
    f32x4 accx[4], accm[4];
#pragma unroll
    for (int j = 0; j < 4; ++j) {
        accx[j] = f32x4{0.f, 0.f, 0.f, 0.f};
        accm[j] = f32x4{0.f, 0.f, 0.f, 0.f};
    }

    const ushort_t* ax = xb + (size_t)(r0 + rlo) * N_SZ + q * 8;
    const ushort_t* am = mub + (size_t)(r0 + rlo) * N_SZ + q * 8;
    const ushort_t* b0 = Wvp + ((size_t)q * N_SZ + w * 64 + rlo) * 8;
#pragma unroll
    for (int s = 0; s < 8; ++s) {
        bf16x8 afx = *(const bf16x8*)(ax + s * 32);
        bf16x8 afm = *(const bf16x8*)(am + s * 32);
        bf16x8 bfr[4];
#pragma unroll
        for (int j = 0; j < 4; ++j)
            bfr[j] = *(const bf16x8*)(b0 + s * 4 * N_SZ * 8 + j * 128);
#pragma unroll
        for (int j = 0; j < 4; ++j) {
            accx[j] = __builtin_amdgcn_mfma_f32_16x16x32_bf16(afx, bfr[j], accx[j], 0, 0, 0);
            accm[j] = __builtin_amdgcn_mfma_f32_16x16x32_bf16(afm, bfr[j], accm[j], 0, 0, 0);
        }
    }
#pragma unroll
    for (int rr = 0; rr < 4; ++rr) {
        float sx = 0.f, sm = 0.f;
#pragma unroll
        for (int j = 0; j < 4; ++j) {
            float vx_ = accx[j][rr]; sx += vx_ * vx_;
            float vm_ = accm[j][rr]; sm += vm_ * vm_;
        }
#pragma unroll
        for (int m = 1; m < 16; m <<= 1) {
            sx += __shfl_xor(sx, m, 64);
            sm += __shfl_xor(sm, m, 64);
        }
        if (rlo == 0) {
            vsx[w][q * 4 + rr] = sx;
            vsm[w][q * 4 + rr] = sm;
        }
    }
    __syncthreads();
    if (tid < 16) {
        vxs[tid] = 1e-3f + vsx[0][tid] + vsx[1][tid] + vsx[2][tid] + vsx[3][tid];
        vms[tid] = 1e-3f + vsm[0][tid] + vsm[1][tid] + vsm[2][tid] + vsm[3][tid];
    }
    __syncthreads();

    // ---- stage 2: epilogue over 16 rows ----
    float t = 0.f;
    const int n = tid;
#pragma unroll 4
    for (int r = 0; r < 16; ++r) {
        size_t row = (size_t)(r0 + r);
        float mu = f[row * 512 + n];
        float lv = f[row * 512 + 256 + n];
        float var = expf(lv);
        float Vx = vxs[r];
        float Vmu = vms[r];
        float scale = fminf(BETA_F * Vx, Vmu) / Vmu;
        float mus = mu * scale;
        out[row * 256 + n] = mus + sqrtf(var) * eps[row * 256 + n];
        float d = y[row * 256 + n] - mus;
        t += lv + d * d / var;
    }
#pragma unroll
    for (int m = 32; m >= 1; m >>= 1) t += __shfl_down(t, m, 64);
    if (lane == 0) red[w] = t;
    __syncthreads();
    if (tid == 0)
        partials[blockIdx.x] = red[0] + red[1] + red[2] + red[3];
}

// sum 512 partials -> logp_y scalar.
__global__ __launch_bounds__(256)
void reduce_kernel(const float* __restrict__ partials, float* __restrict__ out)
{
    int tid = threadIdx.x;
    float s = partials[tid] + partials[tid + 256];
#pragma unroll
    for (int m = 32; m >= 1; m >>= 1) s += __shfl_down(s, m, 64);
    __shared__ float red[4];
    if ((tid & 63) == 0) red[tid >> 6] = s;
    __syncthreads();
    if (tid == 0)
        out[(size_t)B_SZ * N_SZ] =
            0.5f * (red[0] + red[1] + red[2] + red[3] +
                    (float)N_SZ * LOG2PI_F * (float)B_SZ);
}

// Conversion, fully coalesced: one thread per 8-element k-chunk.
__global__ __launch_bounds__(256)
void convert_kernel(const float* __restrict__ x, const float* __restrict__ W1,
                    const float* __restrict__ W2, const float* __restrict__ Wv,
                    ushort_t* __restrict__ xb, ushort_t* __restrict__ W1p,
                    ushort_t* __restrict__ W2p, ushort_t* __restrict__ Wvp)
{
    const int XC = 262144, W1C = 65536, W2C = 131072;
    int c = blockIdx.x * 256 + threadIdx.x;
    if (c < XC) {
        f32x4 a = *(const f32x4*)(x + (size_t)c * 8);
        f32x4 b = *(const f32x4*)(x + (size_t)c * 8 + 4);
        u16x8 o;
#pragma unroll
        for (int i = 0; i < 4; ++i) { o[i] = f2bf(a[i]); o[4 + i] = f2bf(b[i]); }
        *(u16x8*)(xb + (size_t)c * 8) = o;
    } else if (c < XC + W1C) {
        int d = c - XC;
        int ko = d >> 11, n = d & 2047;
        u16x8 o;
#pragma unroll
        for (int ki = 0; ki < 8; ++ki)
            o[ki] = f2bf(W1[(size_t)(ko * 8 + ki) * H_SZ + n]);
        *(u16x8*)(W1p + (size_t)d * 8) = o;
    } else if (c < XC + W1C + W2C) {
        int d = c - XC - W1C;
        int ko = d >> 9, n = d & 511;
        u16x8 o;
#pragma unroll
        for (int ki = 0; ki < 8; ++ki)
            o[ki] = f2bf(W2[(size_t)(ko * 8 + ki) * 512 + n]);
        *(u16x8*)(W2p + (size_t)d * 8) = o;
    } else {
        int d = c - XC - W1C - W2C;
        int ko = d >> 8, n = d & 255;
        u16x8 o;
#pragma unroll
        for (int ki = 0; ki < 8; ++ki)
            o[ki] = f2bf(Wv[(size_t)(ko * 8 + ki) * N_SZ + n]);
        *(u16x8*)(Wvp + (size_t)d * 8) = o;
    }
}

extern "C" void kernel_launch(void* const* d_in, const int* in_sizes, int n_in,
                              void* d_out, int out_size, void* d_ws, size_t ws_size,
                              hipStream_t stream)
{
    const float* x   = (const float*)d_in[0];
    const float* y   = (const float*)d_in[1];
    const float* eps = (const float*)d_in[2];
    const float* W1  = (const float*)d_in[3];
    const float* b1  = (const float*)d_in[4];
    const float* W2  = (const float*)d_in[5];
    const float* b2  = (const float*)d_in[6];
    const float* Wv  = (const float*)d_in[7];
    float* out = (float*)d_out;

    char* ws = (char*)d_ws;
    size_t off = 0;
    auto alloc = [&](size_t bytes) {
        char* p = ws + off;
        off += (bytes + 255) & ~(size_t)255;
        return p;
    };
    ushort_t* xb  = (ushort_t*)alloc((size_t)B_SZ * N_SZ * 2);
    ushort_t* W1p = (ushort_t*)alloc((size_t)N_SZ * H_SZ * 2);
    ushort_t* W2p = (ushort_t*)alloc((size_t)H_SZ * 512 * 2);
    ushort_t* Wvp = (ushort_t*)alloc((size_t)N_SZ * N_SZ * 2);
    ushort_t* hp  = (ushort_t*)alloc((size_t)B_SZ * H_SZ * 2);
    float*    f   = (float*)alloc((size_t)B_SZ * 512 * 4);
    ushort_t* mub = (ushort_t*)alloc((size_t)B_SZ * N_SZ * 2);
    float*    partials = (float*)alloc(512 * 4);

    const int TOTALC = 262144 + 65536 + 131072 + 8192;  // 466944 chunks
    convert_kernel<<<TOTALC / 256, 256, 0, stream>>>(x, W1, W2, Wv, xb, W1p, W2p, Wvp);

    // h_p = tanh(x@W1 + b1) k-permuted, 1024 blocks (4/CU), BK=64
    gemm1_kernel<<<1024, 256, 0, stream>>>(xb, W1p, b1, hp);
    // f = h@W2 + b2 ; mub via LDS transpose, BK=128, A from hp
    gemm2_kernel<<<512, 256, 0, stream>>>(hp, W2p, b2, f, mub);
    // Vx + Vmu + epilogue fused (shared Wv B-frags), 512 blocks
    vmu_epilogue_kernel<<<512, 256, 0, stream>>>(xb, mub, Wvp, f, y, eps, out, partials);
    reduce_kernel<<<1, 256, 0, stream>>>(partials, out);
}